// Round 10
// baseline (742.667 us; speedup 1.0000x reference)
//
#include <hip/hip_runtime.h>
#include <hip/hip_bf16.h>

#define N_NODES 20000
#define NPAD    20224          // node rows padded for tiled layout OOB-safe GEMM reads
#define N_EDGES 320000
#define NGRAPH  64
#define FPD     65

typedef __attribute__((ext_vector_type(8))) __bf16 bf16x8;
typedef __attribute__((ext_vector_type(4))) float floatx4;
typedef __attribute__((ext_vector_type(8))) ushort ushort8v;

__device__ inline float bf2f(ushort u) {
    union { unsigned int i; float f; } c; c.i = ((unsigned int)u) << 16; return c.f;
}
__device__ inline ushort f2bf(float v) {
    __hip_bfloat16 h = __float2bfloat16(v);
    return *(ushort*)&h;
}
// async global->LDS, 16 B per lane; LDS dest must be wave-uniform-base + lane*16
__device__ __forceinline__ void gld_lds16(const ushort* g, ushort* l) {
    __builtin_amdgcn_global_load_lds(
        (const __attribute__((address_space(1))) unsigned int*)g,
        (__attribute__((address_space(3))) unsigned int*)l,
        16, 0, 0);
}

// ---------------- CSR build (rows padded to multiple of 4 edges) ----------------
__global__ void count_in(const int* __restrict__ dst, int* cnt) {
    int e = blockIdx.x * blockDim.x + threadIdx.x;
    if (e < N_EDGES) atomicAdd(&cnt[dst[e]], 1);
}
// prefix-scan of padded (deg+1) counts + D^-1/2 in one kernel (1024 threads)
__global__ __launch_bounds__(1024) void scan_offsets(const int* __restrict__ cnt,
                                                     int* __restrict__ off, int* __restrict__ cursor,
                                                     float* __restrict__ dis) {
    __shared__ int part[1024];
    int t = threadIdx.x;
    const int chunk = (N_NODES + 1023) / 1024;
    int lo = t * chunk, hi = min(lo + chunk, N_NODES);
    int s = 0;
    for (int i = lo; i < hi; ++i) s += (cnt[i] + 4) & ~3;   // (deg+1) padded to x4
    part[t] = s;
    __syncthreads();
    for (int d = 1; d < 1024; d <<= 1) {
        int v = (t >= d) ? part[t - d] : 0;
        __syncthreads();
        part[t] += v;
        __syncthreads();
    }
    int base = part[t] - s;
    for (int i = lo; i < hi; ++i) {
        int c = cnt[i] + 1;                 // + self-loop
        off[i] = base; cursor[i] = base;
        dis[i] = rsqrtf((float)c);
        base += (c + 3) & ~3;
    }
    if (t == 1023) off[N_NODES] = part[1023];
}
// degree-bucket permutation: nodes sorted by padded edge-granule count so waves
// process equal-iteration nodes together (kills gather divergence).
__global__ __launch_bounds__(1024) void build_perm(const int* __restrict__ cnt,
                                                   int* __restrict__ perm) {
    __shared__ int hist[64];
    __shared__ int base[64];
    int t = threadIdx.x;
    if (t < 64) hist[t] = 0;
    __syncthreads();
    for (int i = t; i < N_NODES; i += 1024) {
        int g = ((cnt[i] + 4) & ~3) >> 2;   // iteration count of node i
        atomicAdd(&hist[min(g, 63)], 1);
    }
    __syncthreads();
    if (t == 0) {
        int acc = 0;
        for (int b = 0; b < 64; ++b) { base[b] = acc; acc += hist[b]; }
    }
    __syncthreads();
    for (int i = t; i < N_NODES; i += 1024) {
        int g = ((cnt[i] + 4) & ~3) >> 2;
        int pos = atomicAdd(&base[min(g, 63)], 1);
        perm[pos] = i;
    }
}
__global__ void fill_csr(const int* __restrict__ src, const int* __restrict__ dst,
                         const float* __restrict__ dis, int* cursor,
                         int* __restrict__ esrc, float* __restrict__ ew) {
    int e = blockIdx.x * blockDim.x + threadIdx.x;
    if (e >= N_EDGES + N_NODES) return;
    int s, d; float w;
    if (e < N_EDGES) { s = src[e]; d = dst[e]; w = dis[s] * dis[d]; }
    else { s = d = e - N_EDGES; w = dis[s] * dis[s]; }
    int pos = atomicAdd(&cursor[d], 1);
    esrc[pos] = s; ew[pos] = w;
}
// after fill_csr, cursor[i] == off[i] + real_cnt[i]; pad with zero-weight entries
__global__ void fill_pad(const int* __restrict__ off, const int* __restrict__ cursor,
                         int* __restrict__ esrc, float* __restrict__ ew) {
    int i = blockIdx.x * blockDim.x + threadIdx.x;
    if (i >= N_NODES) return;
    int e1 = off[i + 1];
    for (int e = cursor[i]; e < e1; ++e) { esrc[e] = i; ew[e] = 0.f; }
}

// ---------------- prep_mega: all input-only preprocessing in ONE launch ----------------
__global__ __launch_bounds__(256) void prep_mega(
    const float* __restrict__ x, ushort* __restrict__ xbf,
    const float* __restrict__ W1, ushort* __restrict__ Wt1,
    const float* __restrict__ W2, ushort* __restrict__ Wt2,
    const float* __restrict__ W3, ushort* __restrict__ Wt3,
    const float* __restrict__ Wf1, float* __restrict__ Wf1p,
    const float* __restrict__ fp, float* __restrict__ xc,
    const int* __restrict__ batch, int* __restrict__ gstart)
{
    __shared__ float tsh[32][33];
    int b = blockIdx.x;
    if (b < 25000) {                       // conv: x[N][1280] f32 -> tiled bf16
        int idx = b * 256 + threadIdx.x;   // 25000*256 == 20000*320 exactly
        int n = idx / 320, f4 = idx % 320;
        float4 v = *(const float4*)(x + (size_t)n * 1280 + f4 * 4);
        ushort4 o;
        o.x = f2bf(v.x); o.y = f2bf(v.y); o.z = f2bf(v.z); o.w = f2bf(v.w);
        *(ushort4*)(xbf + (size_t)(f4 >> 4) * (NPAD * 64) + (size_t)n * 64 + (f4 & 15) * 4) = o;
        return;
    }
    b -= 25000;
    if (b < 2600) {                        // W transposes (KP-padded, L2 set-conflict-free)
        const float* W; ushort* Wt; int Nc, KP, kt, nt;
        if (b < 1600)      { W = W1; Wt = Wt1; Nc = 1280; KP = 1344; kt = b % 40; nt = b / 40; }
        else if (b < 2400) { int b2 = b - 1600; W = W2; Wt = Wt2; Nc = 640; KP = 1344; kt = b2 % 40; nt = b2 / 40; }
        else               { int b2 = b - 2400; W = W3; Wt = Wt3; Nc = 320; KP = 704;  kt = b2 % 20; nt = b2 / 20; }
        int k0 = kt * 32, n0 = nt * 32;
        int tx = threadIdx.x & 31, ty = threadIdx.x >> 5;
        #pragma unroll
        for (int i = 0; i < 4; ++i)
            tsh[ty + i * 8][tx] = W[(size_t)(k0 + ty + i * 8) * Nc + n0 + tx];
        __syncthreads();
        #pragma unroll
        for (int i = 0; i < 4; ++i)
            Wt[(size_t)(n0 + ty + i * 8) * KP + k0 + tx] = f2bf(tsh[tx][ty + i * 8]);
        return;
    }
    b -= 2600;
    if (b < 832) {                         // pad Wf1 [193][1024] -> [208][1024]
        int idx = b * 256 + threadIdx.x;
        int k = idx / 1024;
        Wf1p[idx] = (k < 193) ? Wf1[idx] : 0.f;
        return;
    }
    b -= 832;
    if (b < 52) {                          // xc static: fp part + zeros
        int idx = b * 256 + threadIdx.x;
        if (idx < NGRAPH * 208) {
            int g = idx / 208, j = idx % 208;
            xc[idx] = (j < FPD) ? fp[g * FPD + j] : 0.f;
        }
        return;
    }
    b -= 52;
    {                                      // graph_bounds
        int n = b * 256 + threadIdx.x;
        if (n >= N_NODES) return;
        int bb = batch[n];
        int bp = (n == 0) ? -1 : batch[n - 1];
        for (int g = bp + 1; g <= bb; ++g) gstart[g] = n;
        if (n == N_NODES - 1)
            for (int g = bb + 1; g <= NGRAPH; ++g) gstart[g] = N_NODES;
    }
}

// ---------------- bf16 MFMA GEMM, 256x128 tile, wave tile 64x128, BK=64 ----------------
// LDS-BW optimization: wave reads 4 A-frags + 8 B-frags per ks for 32 MFMAs
// (perimeter/area 34 B/kFLOP vs 45.8 of the 64x64 wave tile). 8-granule XOR swizzle
// unchanged: LDS slot (row,g) holds global granule g^(row&7); reads undo it.
__global__ __launch_bounds__(256) void gemm_bf16_256x128(
    const ushort* __restrict__ A, const ushort* __restrict__ Bt,
    ushort* __restrict__ C, int M, int K, int KP, int Nc, int nt, int total, int chunk)
{
    __shared__ ushort As[256 * 64];
    __shared__ ushort Bs[128 * 64];
    const int bi = blockIdx.x;
    const int tile = (bi & 7) * chunk + (bi >> 3);
    if (tile >= total) return;
    const int bm = (tile / nt) * 256, bn = (tile % nt) * 128;

    const int tid = threadIdx.x;
    const int wid = tid >> 6, lane = tid & 63;
    const int quad = lane >> 4, mr = lane & 15;

    floatx4 acc[4][8];
    #pragma unroll
    for (int i = 0; i < 4; ++i)
        #pragma unroll
        for (int j = 0; j < 8; ++j)
            acc[i][j] = (floatx4){0.f, 0.f, 0.f, 0.f};

    for (int k0 = 0; k0 < K; k0 += 64) {
        const ushort* Ak = A + (size_t)(k0 >> 6) * (NPAD * 64);
        #pragma unroll
        for (int i = 0; i < 8; ++i) {          // A: 256 rows x 64k = 8 granules/thread
            int c = tid + i * 256;
            int row = c >> 3, g = c & 7;
            gld_lds16(Ak + (size_t)(bm + row) * 64 + (g ^ (row & 7)) * 8, &As[c * 8]);
        }
        #pragma unroll
        for (int i = 0; i < 4; ++i) {          // B: 128 rows x 64k = 4 granules/thread
            int c = tid + i * 256;
            int row = c >> 3, g = c & 7;
            gld_lds16(Bt + (size_t)(bn + row) * KP + k0 + (g ^ (row & 7)) * 8, &Bs[c * 8]);
        }
        __syncthreads();

        #pragma unroll
        for (int ks = 0; ks < 2; ++ks) {
            bf16x8 af[4], bfv[8];
            #pragma unroll
            for (int t = 0; t < 4; ++t) {
                int ra = wid * 64 + t * 16 + mr;
                af[t] = *(const bf16x8*)&As[ra * 64 + ((ks * 4 + quad) ^ (ra & 7)) * 8];
            }
            #pragma unroll
            for (int t = 0; t < 8; ++t) {
                int rb = t * 16 + mr;
                bfv[t] = *(const bf16x8*)&Bs[rb * 64 + ((ks * 4 + quad) ^ (rb & 7)) * 8];
            }
            #pragma unroll
            for (int tm = 0; tm < 4; ++tm)
                #pragma unroll
                for (int tn = 0; tn < 8; ++tn)
                    acc[tm][tn] = __builtin_amdgcn_mfma_f32_16x16x32_bf16(af[tm], bfv[tn], acc[tm][tn], 0, 0, 0);
        }
        __syncthreads();
    }

    const int cb = bn >> 6;
    #pragma unroll
    for (int tm = 0; tm < 4; ++tm) {
        int rowb = bm + wid * 64 + tm * 16 + quad * 4;
        #pragma unroll
        for (int r = 0; r < 4; ++r) {
            int row = rowb + r;
            if (row < M) {
                #pragma unroll
                for (int tn = 0; tn < 8; ++tn) {
                    ushort* Cc = C + (size_t)(cb + (tn >> 2)) * (NPAD * 64);
                    Cc[(size_t)row * 64 + (tn & 3) * 16 + mr] = f2bf(acc[tm][tn][r]);
                }
            }
        }
    }
}

// legacy 256x64 tile (for Nc % 128 != 0, i.e. layer 3), BK=64, dbuf, tiled A/C
#define STAGE64(AsB, BsB, kt) do {                                                    \
    const ushort* Ak_ = A + (size_t)(kt) * (NPAD * 64);                               \
    const ushort* Bk_ = Bt + (size_t)(kt) * 64;                                       \
    _Pragma("unroll")                                                                 \
    for (int i_ = 0; i_ < 8; ++i_) {                                                  \
        int c_ = tid + i_ * 256;                                                      \
        int row_ = c_ >> 3, g_ = c_ & 7;                                              \
        gld_lds16(Ak_ + (size_t)(bm + row_) * 64 + (g_ ^ (row_ & 7)) * 8, &AsB[c_ * 8]); \
    }                                                                                 \
    _Pragma("unroll")                                                                 \
    for (int i_ = 0; i_ < 2; ++i_) {                                                  \
        int c_ = tid + i_ * 256;                                                      \
        int row_ = c_ >> 3, g_ = c_ & 7;                                              \
        gld_lds16(Bk_ + (size_t)(bn + row_) * KP + (g_ ^ (row_ & 7)) * 8, &BsB[c_ * 8]); \
    }                                                                                 \
} while (0)

#define COMPUTE64(AsB, BsB) do {                                                      \
    _Pragma("unroll")                                                                 \
    for (int ks = 0; ks < 2; ++ks) {                                                  \
        bf16x8 af[4], bfv[4];                                                         \
        _Pragma("unroll")                                                             \
        for (int t = 0; t < 4; ++t) {                                                 \
            int ra = wid * 64 + t * 16 + mr;                                          \
            af[t] = *(const bf16x8*)&AsB[ra * 64 + ((ks * 4 + quad) ^ (ra & 7)) * 8]; \
            int rb = t * 16 + mr;                                                     \
            bfv[t] = *(const bf16x8*)&BsB[rb * 64 + ((ks * 4 + quad) ^ (rb & 7)) * 8];\
        }                                                                             \
        _Pragma("unroll")                                                             \
        for (int tm = 0; tm < 4; ++tm)                                                \
            _Pragma("unroll")                                                         \
            for (int tn = 0; tn < 4; ++tn)                                            \
                acc[tm][tn] = __builtin_amdgcn_mfma_f32_16x16x32_bf16(af[tm], bfv[tn], acc[tm][tn], 0, 0, 0); \
    }                                                                                 \
} while (0)

__global__ __launch_bounds__(256) void gemm_bf16(
    const ushort* __restrict__ A, const ushort* __restrict__ Bt,
    ushort* __restrict__ C, int M, int K, int KP, int Nc, int nt, int total, int chunk)
{
    __shared__ ushort As0[256 * 64], As1[256 * 64];
    __shared__ ushort Bs0[64 * 64], Bs1[64 * 64];
    const int bi = blockIdx.x;
    const int tile = (bi & 7) * chunk + (bi >> 3);
    if (tile >= total) return;
    const int bm = (tile / nt) * 256, bn = (tile % nt) * 64;

    const int tid = threadIdx.x;
    const int wid = tid >> 6, lane = tid & 63;
    const int quad = lane >> 4, mr = lane & 15;

    floatx4 acc[4][4];
    #pragma unroll
    for (int i = 0; i < 4; ++i)
        #pragma unroll
        for (int j = 0; j < 4; ++j)
            acc[i][j] = (floatx4){0.f, 0.f, 0.f, 0.f};

    const int NT = K >> 6;     // 10 for layer 3
    STAGE64(As0, Bs0, 0);
    __syncthreads();
    for (int kt = 0; kt < NT; kt += 2) {
        if (kt + 1 < NT) STAGE64(As1, Bs1, kt + 1);
        COMPUTE64(As0, Bs0);
        __syncthreads();
        if (kt + 1 < NT) {
            if (kt + 2 < NT) STAGE64(As0, Bs0, kt + 2);
            COMPUTE64(As1, Bs1);
            __syncthreads();
        }
    }

    ushort* Cc = C + (size_t)(bn >> 6) * (NPAD * 64);
    #pragma unroll
    for (int tm = 0; tm < 4; ++tm) {
        int rowb = bm + wid * 64 + tm * 16 + quad * 4;
        #pragma unroll
        for (int r = 0; r < 4; ++r) {
            int row = rowb + r;
            if (row < M) {
                #pragma unroll
                for (int tn = 0; tn < 4; ++tn)
                    Cc[(size_t)row * 64 + tn * 16 + mr] = f2bf(acc[tm][tn][r]);
            }
        }
    }
}

static inline void launch_gemm(const ushort* A, const ushort* Bt, ushort* C,
                               int M, int K, int KP, int Nc, hipStream_t stream) {
    if (Nc % 128 == 0) {
        int mt = (M + 255) / 256, nt = Nc / 128;
        int total = mt * nt;
        int chunk = (total + 7) / 8;
        gemm_bf16_256x128<<<8 * chunk, 256, 0, stream>>>(A, Bt, C, M, K, KP, Nc, nt, total, chunk);
    } else {
        int mt = (M + 255) / 256, nt = Nc / 64;
        int total = mt * nt;
        int chunk = (total + 7) / 8;
        gemm_bf16<<<8 * chunk, 256, 0, stream>>>(A, Bt, C, M, K, KP, Nc, nt, total, chunk);
    }
}

// ---------------- CSR gather: tiled layout, degree-sorted nodes, balanced XCD chunks ----
// 2-deep software pipeline: granule i+1's edge record + 4 feature-row loads are issued
// BEFORE granule i's FMAs run on already-resident registers.
template<int TPN>
__global__ __launch_bounds__(256) void gather_tiled(
    const ushort* __restrict__ h, const int* __restrict__ off,
    const int* __restrict__ esrc, const float* __restrict__ ew,
    const float* __restrict__ bias, ushort* __restrict__ out_bf,
    float* __restrict__ out_f32, const int* __restrict__ perm,
    int wbf, int wf32, int nchunks, int nbpc, int cpx)
{
    constexpr int NPB = 256 / TPN;     // nodes per block
    const int bi = blockIdx.x;
    const int t2 = (bi & 7) * cpx + (bi >> 3);
    if (t2 >= nchunks * nbpc) return;
    const int c = t2 / nbpc, nb = t2 - c * nbpc;
    const int tid = threadIdx.x;
    const int g = tid / TPN, t = tid % TPN;
    const int np = nb * NPB + g;
    if (np >= N_NODES) return;
    const int n = perm[np];            // degree-sorted node id

    const ushort* hc = h + (size_t)c * (NPAD * 64) + t * 8;
    float acc[8];
    #pragma unroll
    for (int j = 0; j < 8; ++j) acc[j] = 0.f;

    const int e0 = off[n], e1 = off[n + 1];
    // peel: load granule 0
    int4   s4 = *(const int4*)(esrc + e0);
    float4 w4 = *(const float4*)(ew + e0);
    ushort8v v0 = *(const ushort8v*)(hc + (size_t)s4.x * 64);
    ushort8v v1 = *(const ushort8v*)(hc + (size_t)s4.y * 64);
    ushort8v v2 = *(const ushort8v*)(hc + (size_t)s4.z * 64);
    ushort8v v3 = *(const ushort8v*)(hc + (size_t)s4.w * 64);
    for (int e = e0 + 4; e < e1; e += 4) {
        int4   s4n = *(const int4*)(esrc + e);
        float4 w4n = *(const float4*)(ew + e);
        ushort8v u0 = *(const ushort8v*)(hc + (size_t)s4n.x * 64);
        ushort8v u1 = *(const ushort8v*)(hc + (size_t)s4n.y * 64);
        ushort8v u2 = *(const ushort8v*)(hc + (size_t)s4n.z * 64);
        ushort8v u3 = *(const ushort8v*)(hc + (size_t)s4n.w * 64);
        #pragma unroll
        for (int j = 0; j < 8; ++j)
            acc[j] += w4.x * bf2f(v0[j]) + w4.y * bf2f(v1[j])
                    + w4.z * bf2f(v2[j]) + w4.w * bf2f(v3[j]);
        v0 = u0; v1 = u1; v2 = u2; v3 = u3; w4 = w4n;
    }
    #pragma unroll
    for (int j = 0; j < 8; ++j)
        acc[j] += w4.x * bf2f(v0[j]) + w4.y * bf2f(v1[j])
                + w4.z * bf2f(v2[j]) + w4.w * bf2f(v3[j]);

    const int fb = c * 64 + t * 8;
    float4 b0 = *(const float4*)(bias + fb);
    float4 b1 = *(const float4*)(bias + fb + 4);
    float r[8];
    r[0] = fmaxf(acc[0] + b0.x, 0.f); r[1] = fmaxf(acc[1] + b0.y, 0.f);
    r[2] = fmaxf(acc[2] + b0.z, 0.f); r[3] = fmaxf(acc[3] + b0.w, 0.f);
    r[4] = fmaxf(acc[4] + b1.x, 0.f); r[5] = fmaxf(acc[5] + b1.y, 0.f);
    r[6] = fmaxf(acc[6] + b1.z, 0.f); r[7] = fmaxf(acc[7] + b1.w, 0.f);
    if (wbf) {
        ushort8v o;
        #pragma unroll
        for (int j = 0; j < 8; ++j) o[j] = f2bf(r[j]);
        *(ushort8v*)(out_bf + (size_t)c * (NPAD * 64) + (size_t)n * 64 + t * 8) = o;
    }
    if (wf32) {
        *(float4*)(out_f32 + (size_t)n * (nchunks * 64) + fb)     = make_float4(r[0], r[1], r[2], r[3]);
        *(float4*)(out_f32 + (size_t)n * (nchunks * 64) + fb + 4) = make_float4(r[4], r[5], r[6], r[7]);
    }
}

static inline void launch_gather(const ushort* h, const int* off, const int* esrc,
                                 const float* ew, const float* bias, ushort* out_bf,
                                 float* out_f32, const int* perm,
                                 int wbf, int wf32, int nchunks, hipStream_t stream) {
    constexpr int TPN = 8;
    constexpr int NPB = 256 / TPN;
    const int nbpc = (N_NODES + NPB - 1) / NPB;
    const int total = nchunks * nbpc;
    const int cpx = (total + 7) / 8;
    gather_tiled<TPN><<<8 * cpx, 256, 0, stream>>>(
        h, off, esrc, ew, bias, out_bf, out_f32, perm, wbf, wf32, nchunks, nbpc, cpx);
}

// ---------------- mean pool: 4-way row-split partials, atomic accumulate ----------------
__global__ __launch_bounds__(320) void pool_partial(
    const float* __restrict__ x, const int* __restrict__ gstart, float* __restrict__ pool)
{
    int g = blockIdx.x, q = blockIdx.y;
    int t = threadIdx.x;
    int s = gstart[g], e = gstart[g + 1], len = e - s;
    int lo = s + (len * q) / 4, hi = s + (len * (q + 1)) / 4;
    float a0 = 0.f, a1 = 0.f, a2 = 0.f, a3 = 0.f;
    int n = lo;
    for (; n + 3 < hi; n += 4) {
        a0 += x[(size_t)(n + 0) * 320 + t];
        a1 += x[(size_t)(n + 1) * 320 + t];
        a2 += x[(size_t)(n + 2) * 320 + t];
        a3 += x[(size_t)(n + 3) * 320 + t];
    }
    for (; n < hi; ++n) a0 += x[(size_t)n * 320 + t];
    float acc = (a0 + a1) + (a2 + a3);
    if (hi > lo) atomicAdd(&pool[g * 320 + t], acc);
}

// ---------------- MLP head: split-K GEMM ----------------
template<int K, int SPLIT, int RELU, int SCALE>
__global__ __launch_bounds__(256) void head_gemm_sk(
    const float* __restrict__ in, int istride,
    const float* __restrict__ W, const float* __restrict__ b,
    float* __restrict__ out, int M, int Nc, int ostride, int ooff,
    const int* __restrict__ gs)
{
    constexpr int KQ = K / SPLIT;
    int idx = blockIdx.x * blockDim.x + threadIdx.x;
    int oi = idx / SPLIT, r = idx % SPLIT;
    if (oi >= M * Nc) return;
    int m = oi / Nc, c = oi % Nc;
    const float* ip = in + (size_t)m * istride + r * KQ;
    const float* wp = W + (size_t)r * KQ * Nc + c;
    float a0 = 0.f, a1 = 0.f, a2 = 0.f, a3 = 0.f;
    #pragma unroll
    for (int k = 0; k < KQ; k += 4) {
        float4 v = *(const float4*)(ip + k);
        a0 += v.x * wp[(size_t)(k + 0) * Nc];
        a1 += v.y * wp[(size_t)(k + 1) * Nc];
        a2 += v.z * wp[(size_t)(k + 2) * Nc];
        a3 += v.w * wp[(size_t)(k + 3) * Nc];
    }
    float s = (a0 + a1) + (a2 + a3);
    #pragma unroll
    for (int o = 1; o < SPLIT; o <<= 1) s += __shfl_xor(s, o, 64);
    if (r == 0) {
        if (SCALE) {
            float len = (float)(gs[m + 1] - gs[m]);
            s *= 1.f / fmaxf(len, 1.f);
        }
        s += b[c];
        out[(size_t)m * ostride + ooff + c] = RELU ? fmaxf(s, 0.f) : s;
    }
}

__global__ __launch_bounds__(256) void head_out(
    const float* __restrict__ f2, const float* __restrict__ Wo,
    const float* __restrict__ bo, float* __restrict__ out)
{
    int m = blockIdx.x;
    int t = threadIdx.x;
    float2 v = *(const float2*)(f2 + (size_t)m * 512 + t * 2);
    float2 w = *(const float2*)(Wo + t * 2);
    float s = v.x * w.x + v.y * w.y;
    #pragma unroll
    for (int o = 32; o > 0; o >>= 1) s += __shfl_down(s, o, 64);
    __shared__ float ps[4];
    if ((t & 63) == 0) ps[t >> 6] = s;
    __syncthreads();
    if (t == 0) out[m] = ps[0] + ps[1] + ps[2] + ps[3] + bo[0];
}

extern "C" void kernel_launch(void* const* d_in, const int* in_sizes, int n_in,
                              void* d_out, int out_size, void* d_ws, size_t ws_size,
                              hipStream_t stream) {
    const float* x    = (const float*)d_in[0];
    const int*   eidx = (const int*)d_in[1];
    const int*   batch= (const int*)d_in[2];
    const float* fp_x = (const float*)d_in[3];
    const float* W1 = (const float*)d_in[4];  const float* b1 = (const float*)d_in[5];
    const float* W2 = (const float*)d_in[6];  const float* b2 = (const float*)d_in[7];
    const float* W3 = (const float*)d_in[8];  const float* b3 = (const float*)d_in[9];
    const float* Wg1= (const float*)d_in[10]; const float* bg1= (const float*)d_in[11];
    const float* Wg2= (const float*)d_in[12]; const float* bg2= (const float*)d_in[13];
    const float* Wf1= (const float*)d_in[14]; const float* bf1= (const float*)d_in[15];
    const float* Wf2= (const float*)d_in[16]; const float* bf2= (const float*)d_in[17];
    const float* Wo = (const float*)d_in[18]; const float* bo = (const float*)d_in[19];
    float* out = (float*)d_out;

    const int* src = eidx;
    const int* dst = eidx + N_EDGES;

    // ---- workspace layout (all offsets 16-B aligned) ----
    char* p = (char*)d_ws;
    float* dis   = (float*)p;  p += 20480 * 4;
    int*   cntI  = (int*)p;    p += 20480 * 4;
    int*   off   = (int*)p;    p += 20480 * 4;
    int*   cursor= (int*)p;    p += 20480 * 4;
    int*   perm  = (int*)p;    p += 20480 * 4;
    int*   gstart= (int*)p;    p += 128 * 4;
    int*   esrc  = (int*)p;    p += 402432 * 4;
    float* ew    = (float*)p;  p += 402432 * 4;
    ushort* xbf  = (ushort*)p; p += (size_t)NPAD * 1280 * 2;
    ushort* hbf  = (ushort*)p; p += (size_t)NPAD * 1280 * 2;
    ushort* abf  = (ushort*)p; p += (size_t)NPAD * 1280 * 2;
    float* a3f   = (float*)p;  p += (size_t)N_NODES * 320 * 4;
    ushort* Wt1  = (ushort*)p; p += (size_t)1280 * 1344 * 2;
    ushort* Wt2  = (ushort*)p; p += (size_t)640 * 1344 * 2;
    ushort* Wt3  = (ushort*)p; p += (size_t)320 * 704 * 2;
    float* pool  = (float*)p;  p += NGRAPH * 320 * 4;
    float* m1    = (float*)p;  p += NGRAPH * 1024 * 4;
    float* xc    = (float*)p;  p += NGRAPH * 208 * 4;
    float* f1    = (float*)p;  p += NGRAPH * 1024 * 4;
    float* f2    = (float*)p;  p += NGRAPH * 512 * 4;
    float* Wf1p  = (float*)p;  p += 208 * 1024 * 4;

    // ---- zero accumulators (stream-ordered, graph-capturable) ----
    hipMemsetAsync(cntI, 0, N_NODES * 4, stream);
    hipMemsetAsync(pool, 0, NGRAPH * 320 * 4, stream);

    // ---- all input-only preprocessing in one launch ----
    prep_mega<<<25000 + 2600 + 832 + 52 + 79, 256, 0, stream>>>(
        x, xbf, W1, Wt1, W2, Wt2, W3, Wt3, Wf1, Wf1p, fp_x, xc, batch, gstart);

    // ---- CSR build ----
    count_in<<<(N_EDGES + 255) / 256, 256, 0, stream>>>(dst, cntI);
    build_perm<<<1, 1024, 0, stream>>>(cntI, perm);
    scan_offsets<<<1, 1024, 0, stream>>>(cntI, off, cursor, dis);
    fill_csr<<<(N_EDGES + N_NODES + 255) / 256, 256, 0, stream>>>(src, dst, dis, cursor, esrc, ew);
    fill_pad<<<(N_NODES + 255) / 256, 256, 0, stream>>>(off, cursor, esrc, ew);

    // ---- layer 1 ----
    launch_gemm(xbf, Wt1, hbf, N_NODES, 1280, 1344, 1280, stream);
    launch_gather(hbf, off, esrc, ew, b1, abf, (float*)nullptr, perm, 1, 0, 20, stream);
    // ---- layer 2 ----
    launch_gemm(abf, Wt2, hbf, N_NODES, 1280, 1344, 640, stream);
    launch_gather(hbf, off, esrc, ew, b2, abf, (float*)nullptr, perm, 1, 0, 10, stream);
    // ---- layer 3 ----
    launch_gemm(abf, Wt3, hbf, N_NODES, 640, 704, 320, stream);
    launch_gather(hbf, off, esrc, ew, b3, (ushort*)nullptr, a3f, perm, 0, 1, 5, stream);

    // ---- global mean pool (partials; 1/cnt folded into g1 GEMM) ----
    pool_partial<<<dim3(NGRAPH, 4), 320, 0, stream>>>(a3f, gstart, pool);

    // ---- MLP head (split-K) ----
    head_gemm_sk<320, 4, 1, 1><<<(NGRAPH * 1024 * 4 + 255) / 256, 256, 0, stream>>>(
        pool, 320, Wg1, bg1, m1, NGRAPH, 1024, 1024, 0, gstart);
    head_gemm_sk<1024, 8, 0, 0><<<(NGRAPH * 128 * 8 + 255) / 256, 256, 0, stream>>>(
        m1, 1024, Wg2, bg2, xc, NGRAPH, 128, 208, FPD, (const int*)nullptr);
    head_gemm_sk<208, 4, 1, 0><<<(NGRAPH * 1024 * 4 + 255) / 256, 256, 0, stream>>>(
        xc, 208, Wf1p, bf1, f1, NGRAPH, 1024, 1024, 0, (const int*)nullptr);
    head_gemm_sk<1024, 8, 1, 0><<<(NGRAPH * 512 * 8 + 255) / 256, 256, 0, stream>>>(
        f1, 1024, Wf2, bf2, f2, NGRAPH, 512, 512, 0, (const int*)nullptr);
    head_out<<<NGRAPH, 256, 0, stream>>>(f2, Wo, bo, out);
}

// Round 11
// 663.932 us; speedup vs baseline: 1.1186x; 1.1186x over previous
//
#include <hip/hip_runtime.h>
#include <hip/hip_bf16.h>

#define N_NODES 20000
#define NPAD    20224          // node rows padded for tiled layout OOB-safe GEMM reads
#define N_EDGES 320000
#define NGRAPH  64
#define FPD     65

typedef __attribute__((ext_vector_type(8))) __bf16 bf16x8;
typedef __attribute__((ext_vector_type(4))) float floatx4;
typedef __attribute__((ext_vector_type(8))) ushort ushort8v;

__device__ inline float bf2f(ushort u) {
    union { unsigned int i; float f; } c; c.i = ((unsigned int)u) << 16; return c.f;
}
__device__ inline ushort f2bf(float v) {
    __hip_bfloat16 h = __float2bfloat16(v);
    return *(ushort*)&h;
}
// async global->LDS, 16 B per lane; LDS dest must be wave-uniform-base + lane*16
__device__ __forceinline__ void gld_lds16(const ushort* g, ushort* l) {
    __builtin_amdgcn_global_load_lds(
        (const __attribute__((address_space(1))) unsigned int*)g,
        (__attribute__((address_space(3))) unsigned int*)l,
        16, 0, 0);
}

// ---------------- CSR build (rows padded to multiple of 4 edges) ----------------
__global__ void count_in(const int* __restrict__ dst, int* cnt) {
    int e = blockIdx.x * blockDim.x + threadIdx.x;
    if (e < N_EDGES) atomicAdd(&cnt[dst[e]], 1);
}
// prefix-scan of padded (deg+1) counts + D^-1/2 in one kernel (1024 threads)
__global__ __launch_bounds__(1024) void scan_offsets(const int* __restrict__ cnt,
                                                     int* __restrict__ off, int* __restrict__ cursor,
                                                     float* __restrict__ dis) {
    __shared__ int part[1024];
    int t = threadIdx.x;
    const int chunk = (N_NODES + 1023) / 1024;
    int lo = t * chunk, hi = min(lo + chunk, N_NODES);
    int s = 0;
    for (int i = lo; i < hi; ++i) s += (cnt[i] + 4) & ~3;   // (deg+1) padded to x4
    part[t] = s;
    __syncthreads();
    for (int d = 1; d < 1024; d <<= 1) {
        int v = (t >= d) ? part[t - d] : 0;
        __syncthreads();
        part[t] += v;
        __syncthreads();
    }
    int base = part[t] - s;
    for (int i = lo; i < hi; ++i) {
        int c = cnt[i] + 1;                 // + self-loop
        off[i] = base; cursor[i] = base;
        dis[i] = rsqrtf((float)c);
        base += (c + 3) & ~3;
    }
    if (t == 1023) off[N_NODES] = part[1023];
}
// degree-bucket permutation: nodes sorted by padded edge-granule count so waves
// process equal-iteration nodes together (kills gather divergence).
__global__ __launch_bounds__(1024) void build_perm(const int* __restrict__ cnt,
                                                   int* __restrict__ perm) {
    __shared__ int hist[64];
    __shared__ int base[64];
    int t = threadIdx.x;
    if (t < 64) hist[t] = 0;
    __syncthreads();
    for (int i = t; i < N_NODES; i += 1024) {
        int g = ((cnt[i] + 4) & ~3) >> 2;   // iteration count of node i
        atomicAdd(&hist[min(g, 63)], 1);
    }
    __syncthreads();
    if (t == 0) {
        int acc = 0;
        for (int b = 0; b < 64; ++b) { base[b] = acc; acc += hist[b]; }
    }
    __syncthreads();
    for (int i = t; i < N_NODES; i += 1024) {
        int g = ((cnt[i] + 4) & ~3) >> 2;
        int pos = atomicAdd(&base[min(g, 63)], 1);
        perm[pos] = i;
    }
}
__global__ void fill_csr(const int* __restrict__ src, const int* __restrict__ dst,
                         const float* __restrict__ dis, int* cursor,
                         int* __restrict__ esrc, float* __restrict__ ew) {
    int e = blockIdx.x * blockDim.x + threadIdx.x;
    if (e >= N_EDGES + N_NODES) return;
    int s, d; float w;
    if (e < N_EDGES) { s = src[e]; d = dst[e]; w = dis[s] * dis[d]; }
    else { s = d = e - N_EDGES; w = dis[s] * dis[s]; }
    int pos = atomicAdd(&cursor[d], 1);
    esrc[pos] = s; ew[pos] = w;
}
// after fill_csr, cursor[i] == off[i] + real_cnt[i]; pad with zero-weight entries
__global__ void fill_pad(const int* __restrict__ off, const int* __restrict__ cursor,
                         int* __restrict__ esrc, float* __restrict__ ew) {
    int i = blockIdx.x * blockDim.x + threadIdx.x;
    if (i >= N_NODES) return;
    int e1 = off[i + 1];
    for (int e = cursor[i]; e < e1; ++e) { esrc[e] = i; ew[e] = 0.f; }
}

// ---------------- prep_mega: all input-only preprocessing in ONE launch ----------------
__global__ __launch_bounds__(256) void prep_mega(
    const float* __restrict__ x, ushort* __restrict__ xbf,
    const float* __restrict__ W1, ushort* __restrict__ Wt1,
    const float* __restrict__ W2, ushort* __restrict__ Wt2,
    const float* __restrict__ W3, ushort* __restrict__ Wt3,
    const float* __restrict__ Wf1, float* __restrict__ Wf1p,
    const float* __restrict__ fp, float* __restrict__ xc,
    const int* __restrict__ batch, int* __restrict__ gstart)
{
    __shared__ float tsh[32][33];
    int b = blockIdx.x;
    if (b < 25000) {                       // conv: x[N][1280] f32 -> tiled bf16
        int idx = b * 256 + threadIdx.x;   // 25000*256 == 20000*320 exactly
        int n = idx / 320, f4 = idx % 320;
        float4 v = *(const float4*)(x + (size_t)n * 1280 + f4 * 4);
        ushort4 o;
        o.x = f2bf(v.x); o.y = f2bf(v.y); o.z = f2bf(v.z); o.w = f2bf(v.w);
        *(ushort4*)(xbf + (size_t)(f4 >> 4) * (NPAD * 64) + (size_t)n * 64 + (f4 & 15) * 4) = o;
        return;
    }
    b -= 25000;
    if (b < 2600) {                        // W transposes (KP-padded, L2 set-conflict-free)
        const float* W; ushort* Wt; int Nc, KP, kt, nt;
        if (b < 1600)      { W = W1; Wt = Wt1; Nc = 1280; KP = 1344; kt = b % 40; nt = b / 40; }
        else if (b < 2400) { int b2 = b - 1600; W = W2; Wt = Wt2; Nc = 640; KP = 1344; kt = b2 % 40; nt = b2 / 40; }
        else               { int b2 = b - 2400; W = W3; Wt = Wt3; Nc = 320; KP = 704;  kt = b2 % 20; nt = b2 / 20; }
        int k0 = kt * 32, n0 = nt * 32;
        int tx = threadIdx.x & 31, ty = threadIdx.x >> 5;
        #pragma unroll
        for (int i = 0; i < 4; ++i)
            tsh[ty + i * 8][tx] = W[(size_t)(k0 + ty + i * 8) * Nc + n0 + tx];
        __syncthreads();
        #pragma unroll
        for (int i = 0; i < 4; ++i)
            Wt[(size_t)(n0 + ty + i * 8) * KP + k0 + tx] = f2bf(tsh[tx][ty + i * 8]);
        return;
    }
    b -= 2600;
    if (b < 832) {                         // pad Wf1 [193][1024] -> [208][1024]
        int idx = b * 256 + threadIdx.x;
        int k = idx / 1024;
        Wf1p[idx] = (k < 193) ? Wf1[idx] : 0.f;
        return;
    }
    b -= 832;
    if (b < 52) {                          // xc static: fp part + zeros
        int idx = b * 256 + threadIdx.x;
        if (idx < NGRAPH * 208) {
            int g = idx / 208, j = idx % 208;
            xc[idx] = (j < FPD) ? fp[g * FPD + j] : 0.f;
        }
        return;
    }
    b -= 52;
    {                                      // graph_bounds
        int n = b * 256 + threadIdx.x;
        if (n >= N_NODES) return;
        int bb = batch[n];
        int bp = (n == 0) ? -1 : batch[n - 1];
        for (int g = bp + 1; g <= bb; ++g) gstart[g] = n;
        if (n == N_NODES - 1)
            for (int g = bb + 1; g <= NGRAPH; ++g) gstart[g] = N_NODES;
    }
}

// ---------------- bf16 MFMA GEMM, BK=64, 2-phase double-buffered LDS ----------------
// 8-granule XOR swizzle: LDS slot (row,g) holds global granule g^(row&7); reads undo it.

#define STAGE128(AsB, BsB, kt) do {                                                   \
    const ushort* Ak_ = A + (size_t)(kt) * (NPAD * 64);                               \
    const ushort* Bk_ = Bt + (size_t)(kt) * 64;                                       \
    _Pragma("unroll")                                                                 \
    for (int i_ = 0; i_ < 4; ++i_) {                                                  \
        int c_ = tid + i_ * 256;                                                      \
        int row_ = c_ >> 3, g_ = c_ & 7;                                              \
        gld_lds16(Ak_ + (size_t)(bm + row_) * 64 + (g_ ^ (row_ & 7)) * 8, &AsB[c_ * 8]); \
    }                                                                                 \
    _Pragma("unroll")                                                                 \
    for (int i_ = 0; i_ < 4; ++i_) {                                                  \
        int c_ = tid + i_ * 256;                                                      \
        int row_ = c_ >> 3, g_ = c_ & 7;                                              \
        gld_lds16(Bk_ + (size_t)(bn + row_) * KP + (g_ ^ (row_ & 7)) * 8, &BsB[c_ * 8]); \
    }                                                                                 \
} while (0)

#define COMPUTE128(AsB, BsB) do {                                                     \
    _Pragma("unroll")                                                                 \
    for (int ks = 0; ks < 2; ++ks) {                                                  \
        bf16x8 af[4], bfv[4];                                                         \
        _Pragma("unroll")                                                             \
        for (int t = 0; t < 4; ++t) {                                                 \
            int ra = wr * 64 + t * 16 + mr;                                           \
            af[t] = *(const bf16x8*)&AsB[ra * 64 + ((ks * 4 + quad) ^ (ra & 7)) * 8]; \
            int rb = wc * 64 + t * 16 + mr;                                           \
            bfv[t] = *(const bf16x8*)&BsB[rb * 64 + ((ks * 4 + quad) ^ (rb & 7)) * 8];\
        }                                                                             \
        _Pragma("unroll")                                                             \
        for (int tm = 0; tm < 4; ++tm)                                                \
            _Pragma("unroll")                                                         \
            for (int tn = 0; tn < 4; ++tn)                                            \
                acc[tm][tn] = __builtin_amdgcn_mfma_f32_16x16x32_bf16(af[tm], bfv[tn], acc[tm][tn], 0, 0, 0); \
    }                                                                                 \
} while (0)

__global__ __launch_bounds__(256) void gemm_bf16_128(
    const ushort* __restrict__ A, const ushort* __restrict__ Bt,
    ushort* __restrict__ C, int M, int K, int KP, int Nc, int nt, int total, int chunk)
{
    __shared__ ushort As0[128 * 64], As1[128 * 64];
    __shared__ ushort Bs0[128 * 64], Bs1[128 * 64];
    const int bi = blockIdx.x;
    const int tile = (bi & 7) * chunk + (bi >> 3);
    if (tile >= total) return;
    const int bm = (tile / nt) * 128, bn = (tile % nt) * 128;

    const int tid = threadIdx.x;
    const int wid = tid >> 6, lane = tid & 63;
    const int wr = wid >> 1, wc = wid & 1;
    const int quad = lane >> 4, mr = lane & 15;

    floatx4 acc[4][4];
    #pragma unroll
    for (int i = 0; i < 4; ++i)
        #pragma unroll
        for (int j = 0; j < 4; ++j)
            acc[i][j] = (floatx4){0.f, 0.f, 0.f, 0.f};

    const int NT = K >> 6;     // even for all layers (20 / 20 / 10)
    STAGE128(As0, Bs0, 0);
    __syncthreads();
    for (int kt = 0; kt < NT; kt += 2) {
        if (kt + 1 < NT) STAGE128(As1, Bs1, kt + 1);
        COMPUTE128(As0, Bs0);
        __syncthreads();
        if (kt + 1 < NT) {
            if (kt + 2 < NT) STAGE128(As0, Bs0, kt + 2);
            COMPUTE128(As1, Bs1);
            __syncthreads();
        }
    }

    ushort* Cc = C + (size_t)((bn >> 6) + wc) * (NPAD * 64);
    #pragma unroll
    for (int tm = 0; tm < 4; ++tm) {
        int rowb = bm + wr * 64 + tm * 16 + quad * 4;
        #pragma unroll
        for (int r = 0; r < 4; ++r) {
            int row = rowb + r;
            if (row < M) {
                #pragma unroll
                for (int tn = 0; tn < 4; ++tn)
                    Cc[(size_t)row * 64 + tn * 16 + mr] = f2bf(acc[tm][tn][r]);
            }
        }
    }
}

// legacy 256x64 tile (for Nc % 128 != 0, i.e. layer 3), BK=64, dbuf, tiled A/C
#define STAGE64(AsB, BsB, kt) do {                                                    \
    const ushort* Ak_ = A + (size_t)(kt) * (NPAD * 64);                               \
    const ushort* Bk_ = Bt + (size_t)(kt) * 64;                                       \
    _Pragma("unroll")                                                                 \
    for (int i_ = 0; i_ < 8; ++i_) {                                                  \
        int c_ = tid + i_ * 256;                                                      \
        int row_ = c_ >> 3, g_ = c_ & 7;                                              \
        gld_lds16(Ak_ + (size_t)(bm + row_) * 64 + (g_ ^ (row_ & 7)) * 8, &AsB[c_ * 8]); \
    }                                                                                 \
    _Pragma("unroll")                                                                 \
    for (int i_ = 0; i_ < 2; ++i_) {                                                  \
        int c_ = tid + i_ * 256;                                                      \
        int row_ = c_ >> 3, g_ = c_ & 7;                                              \
        gld_lds16(Bk_ + (size_t)(bn + row_) * KP + (g_ ^ (row_ & 7)) * 8, &BsB[c_ * 8]); \
    }                                                                                 \
} while (0)

#define COMPUTE64(AsB, BsB) do {                                                      \
    _Pragma("unroll")                                                                 \
    for (int ks = 0; ks < 2; ++ks) {                                                  \
        bf16x8 af[4], bfv[4];                                                         \
        _Pragma("unroll")                                                             \
        for (int t = 0; t < 4; ++t) {                                                 \
            int ra = wid * 64 + t * 16 + mr;                                          \
            af[t] = *(const bf16x8*)&AsB[ra * 64 + ((ks * 4 + quad) ^ (ra & 7)) * 8]; \
            int rb = t * 16 + mr;                                                     \
            bfv[t] = *(const bf16x8*)&BsB[rb * 64 + ((ks * 4 + quad) ^ (rb & 7)) * 8];\
        }                                                                             \
        _Pragma("unroll")                                                             \
        for (int tm = 0; tm < 4; ++tm)                                                \
            _Pragma("unroll")                                                         \
            for (int tn = 0; tn < 4; ++tn)                                            \
                acc[tm][tn] = __builtin_amdgcn_mfma_f32_16x16x32_bf16(af[tm], bfv[tn], acc[tm][tn], 0, 0, 0); \
    }                                                                                 \
} while (0)

__global__ __launch_bounds__(256) void gemm_bf16(
    const ushort* __restrict__ A, const ushort* __restrict__ Bt,
    ushort* __restrict__ C, int M, int K, int KP, int Nc, int nt, int total, int chunk)
{
    __shared__ ushort As0[256 * 64], As1[256 * 64];
    __shared__ ushort Bs0[64 * 64], Bs1[64 * 64];
    const int bi = blockIdx.x;
    const int tile = (bi & 7) * chunk + (bi >> 3);
    if (tile >= total) return;
    const int bm = (tile / nt) * 256, bn = (tile % nt) * 64;

    const int tid = threadIdx.x;
    const int wid = tid >> 6, lane = tid & 63;
    const int quad = lane >> 4, mr = lane & 15;

    floatx4 acc[4][4];
    #pragma unroll
    for (int i = 0; i < 4; ++i)
        #pragma unroll
        for (int j = 0; j < 4; ++j)
            acc[i][j] = (floatx4){0.f, 0.f, 0.f, 0.f};

    const int NT = K >> 6;     // 10 for layer 3
    STAGE64(As0, Bs0, 0);
    __syncthreads();
    for (int kt = 0; kt < NT; kt += 2) {
        if (kt + 1 < NT) STAGE64(As1, Bs1, kt + 1);
        COMPUTE64(As0, Bs0);
        __syncthreads();
        if (kt + 1 < NT) {
            if (kt + 2 < NT) STAGE64(As0, Bs0, kt + 2);
            COMPUTE64(As1, Bs1);
            __syncthreads();
        }
    }

    ushort* Cc = C + (size_t)(bn >> 6) * (NPAD * 64);
    #pragma unroll
    for (int tm = 0; tm < 4; ++tm) {
        int rowb = bm + wid * 64 + tm * 16 + quad * 4;
        #pragma unroll
        for (int r = 0; r < 4; ++r) {
            int row = rowb + r;
            if (row < M) {
                #pragma unroll
                for (int tn = 0; tn < 4; ++tn)
                    Cc[(size_t)row * 64 + tn * 16 + mr] = f2bf(acc[tm][tn][r]);
            }
        }
    }
}

static inline void launch_gemm(const ushort* A, const ushort* Bt, ushort* C,
                               int M, int K, int KP, int Nc, hipStream_t stream) {
    if (Nc % 128 == 0) {
        int mt = (M + 127) / 128, nt = Nc / 128;
        int total = mt * nt;
        int chunk = (total + 7) / 8;
        gemm_bf16_128<<<8 * chunk, 256, 0, stream>>>(A, Bt, C, M, K, KP, Nc, nt, total, chunk);
    } else {
        int mt = (M + 255) / 256, nt = Nc / 64;
        int total = mt * nt;
        int chunk = (total + 7) / 8;
        gemm_bf16<<<8 * chunk, 256, 0, stream>>>(A, Bt, C, M, K, KP, Nc, nt, total, chunk);
    }
}

// ---------------- CSR gather: tiled layout, degree-sorted nodes, balanced XCD chunks ----
// 2-deep software pipeline: granule i+1's edge record + 4 feature-row loads are issued
// BEFORE granule i's FMAs run on already-resident registers.
template<int TPN>
__global__ __launch_bounds__(256) void gather_tiled(
    const ushort* __restrict__ h, const int* __restrict__ off,
    const int* __restrict__ esrc, const float* __restrict__ ew,
    const float* __restrict__ bias, ushort* __restrict__ out_bf,
    float* __restrict__ out_f32, const int* __restrict__ perm,
    int wbf, int wf32, int nchunks, int nbpc, int cpx)
{
    constexpr int NPB = 256 / TPN;     // nodes per block
    const int bi = blockIdx.x;
    const int t2 = (bi & 7) * cpx + (bi >> 3);
    if (t2 >= nchunks * nbpc) return;
    const int c = t2 / nbpc, nb = t2 - c * nbpc;
    const int tid = threadIdx.x;
    const int g = tid / TPN, t = tid % TPN;
    const int np = nb * NPB + g;
    if (np >= N_NODES) return;
    const int n = perm[np];            // degree-sorted node id

    const ushort* hc = h + (size_t)c * (NPAD * 64) + t * 8;
    float acc[8];
    #pragma unroll
    for (int j = 0; j < 8; ++j) acc[j] = 0.f;

    const int e0 = off[n], e1 = off[n + 1];
    // peel: load granule 0
    int4   s4 = *(const int4*)(esrc + e0);
    float4 w4 = *(const float4*)(ew + e0);
    ushort8v v0 = *(const ushort8v*)(hc + (size_t)s4.x * 64);
    ushort8v v1 = *(const ushort8v*)(hc + (size_t)s4.y * 64);
    ushort8v v2 = *(const ushort8v*)(hc + (size_t)s4.z * 64);
    ushort8v v3 = *(const ushort8v*)(hc + (size_t)s4.w * 64);
    for (int e = e0 + 4; e < e1; e += 4) {
        int4   s4n = *(const int4*)(esrc + e);
        float4 w4n = *(const float4*)(ew + e);
        ushort8v u0 = *(const ushort8v*)(hc + (size_t)s4n.x * 64);
        ushort8v u1 = *(const ushort8v*)(hc + (size_t)s4n.y * 64);
        ushort8v u2 = *(const ushort8v*)(hc + (size_t)s4n.z * 64);
        ushort8v u3 = *(const ushort8v*)(hc + (size_t)s4n.w * 64);
        #pragma unroll
        for (int j = 0; j < 8; ++j)
            acc[j] += w4.x * bf2f(v0[j]) + w4.y * bf2f(v1[j])
                    + w4.z * bf2f(v2[j]) + w4.w * bf2f(v3[j]);
        v0 = u0; v1 = u1; v2 = u2; v3 = u3; w4 = w4n;
    }
    #pragma unroll
    for (int j = 0; j < 8; ++j)
        acc[j] += w4.x * bf2f(v0[j]) + w4.y * bf2f(v1[j])
                + w4.z * bf2f(v2[j]) + w4.w * bf2f(v3[j]);

    const int fb = c * 64 + t * 8;
    float4 b0 = *(const float4*)(bias + fb);
    float4 b1 = *(const float4*)(bias + fb + 4);
    float r[8];
    r[0] = fmaxf(acc[0] + b0.x, 0.f); r[1] = fmaxf(acc[1] + b0.y, 0.f);
    r[2] = fmaxf(acc[2] + b0.z, 0.f); r[3] = fmaxf(acc[3] + b0.w, 0.f);
    r[4] = fmaxf(acc[4] + b1.x, 0.f); r[5] = fmaxf(acc[5] + b1.y, 0.f);
    r[6] = fmaxf(acc[6] + b1.z, 0.f); r[7] = fmaxf(acc[7] + b1.w, 0.f);
    if (wbf) {
        ushort8v o;
        #pragma unroll
        for (int j = 0; j < 8; ++j) o[j] = f2bf(r[j]);
        *(ushort8v*)(out_bf + (size_t)c * (NPAD * 64) + (size_t)n * 64 + t * 8) = o;
    }
    if (wf32) {
        *(float4*)(out_f32 + (size_t)n * (nchunks * 64) + fb)     = make_float4(r[0], r[1], r[2], r[3]);
        *(float4*)(out_f32 + (size_t)n * (nchunks * 64) + fb + 4) = make_float4(r[4], r[5], r[6], r[7]);
    }
}

static inline void launch_gather(const ushort* h, const int* off, const int* esrc,
                                 const float* ew, const float* bias, ushort* out_bf,
                                 float* out_f32, const int* perm,
                                 int wbf, int wf32, int nchunks, hipStream_t stream) {
    constexpr int TPN = 8;
    constexpr int NPB = 256 / TPN;
    const int nbpc = (N_NODES + NPB - 1) / NPB;
    const int total = nchunks * nbpc;
    const int cpx = (total + 7) / 8;
    gather_tiled<TPN><<<8 * cpx, 256, 0, stream>>>(
        h, off, esrc, ew, bias, out_bf, out_f32, perm, wbf, wf32, nchunks, nbpc, cpx);
}

// ---------------- mean pool: 4-way row-split partials, atomic accumulate ----------------
__global__ __launch_bounds__(320) void pool_partial(
    const float* __restrict__ x, const int* __restrict__ gstart, float* __restrict__ pool)
{
    int g = blockIdx.x, q = blockIdx.y;
    int t = threadIdx.x;
    int s = gstart[g], e = gstart[g + 1], len = e - s;
    int lo = s + (len * q) / 4, hi = s + (len * (q + 1)) / 4;
    float a0 = 0.f, a1 = 0.f, a2 = 0.f, a3 = 0.f;
    int n = lo;
    for (; n + 3 < hi; n += 4) {
        a0 += x[(size_t)(n + 0) * 320 + t];
        a1 += x[(size_t)(n + 1) * 320 + t];
        a2 += x[(size_t)(n + 2) * 320 + t];
        a3 += x[(size_t)(n + 3) * 320 + t];
    }
    for (; n < hi; ++n) a0 += x[(size_t)n * 320 + t];
    float acc = (a0 + a1) + (a2 + a3);
    if (hi > lo) atomicAdd(&pool[g * 320 + t], acc);
}

// ---------------- MLP head: split-K GEMM ----------------
template<int K, int SPLIT, int RELU, int SCALE>
__global__ __launch_bounds__(256) void head_gemm_sk(
    const float* __restrict__ in, int istride,
    const float* __restrict__ W, const float* __restrict__ b,
    float* __restrict__ out, int M, int Nc, int ostride, int ooff,
    const int* __restrict__ gs)
{
    constexpr int KQ = K / SPLIT;
    int idx = blockIdx.x * blockDim.x + threadIdx.x;
    int oi = idx / SPLIT, r = idx % SPLIT;
    if (oi >= M * Nc) return;
    int m = oi / Nc, c = oi % Nc;
    const float* ip = in + (size_t)m * istride + r * KQ;
    const float* wp = W + (size_t)r * KQ * Nc + c;
    float a0 = 0.f, a1 = 0.f, a2 = 0.f, a3 = 0.f;
    #pragma unroll
    for (int k = 0; k < KQ; k += 4) {
        float4 v = *(const float4*)(ip + k);
        a0 += v.x * wp[(size_t)(k + 0) * Nc];
        a1 += v.y * wp[(size_t)(k + 1) * Nc];
        a2 += v.z * wp[(size_t)(k + 2) * Nc];
        a3 += v.w * wp[(size_t)(k + 3) * Nc];
    }
    float s = (a0 + a1) + (a2 + a3);
    #pragma unroll
    for (int o = 1; o < SPLIT; o <<= 1) s += __shfl_xor(s, o, 64);
    if (r == 0) {
        if (SCALE) {
            float len = (float)(gs[m + 1] - gs[m]);
            s *= 1.f / fmaxf(len, 1.f);
        }
        s += b[c];
        out[(size_t)m * ostride + ooff + c] = RELU ? fmaxf(s, 0.f) : s;
    }
}

__global__ __launch_bounds__(256) void head_out(
    const float* __restrict__ f2, const float* __restrict__ Wo,
    const float* __restrict__ bo, float* __restrict__ out)
{
    int m = blockIdx.x;
    int t = threadIdx.x;
    float2 v = *(const float2*)(f2 + (size_t)m * 512 + t * 2);
    float2 w = *(const float2*)(Wo + t * 2);
    float s = v.x * w.x + v.y * w.y;
    #pragma unroll
    for (int o = 32; o > 0; o >>= 1) s += __shfl_down(s, o, 64);
    __shared__ float ps[4];
    if ((t & 63) == 0) ps[t >> 6] = s;
    __syncthreads();
    if (t == 0) out[m] = ps[0] + ps[1] + ps[2] + ps[3] + bo[0];
}

extern "C" void kernel_launch(void* const* d_in, const int* in_sizes, int n_in,
                              void* d_out, int out_size, void* d_ws, size_t ws_size,
                              hipStream_t stream) {
    const float* x    = (const float*)d_in[0];
    const int*   eidx = (const int*)d_in[1];
    const int*   batch= (const int*)d_in[2];
    const float* fp_x = (const float*)d_in[3];
    const float* W1 = (const float*)d_in[4];  const float* b1 = (const float*)d_in[5];
    const float* W2 = (const float*)d_in[6];  const float* b2 = (const float*)d_in[7];
    const float* W3 = (const float*)d_in[8];  const float* b3 = (const float*)d_in[9];
    const float* Wg1= (const float*)d_in[10]; const float* bg1= (const float*)d_in[11];
    const float* Wg2= (const float*)d_in[12]; const float* bg2= (const float*)d_in[13];
    const float* Wf1= (const float*)d_in[14]; const float* bf1= (const float*)d_in[15];
    const float* Wf2= (const float*)d_in[16]; const float* bf2= (const float*)d_in[17];
    const float* Wo = (const float*)d_in[18]; const float* bo = (const float*)d_in[19];
    float* out = (float*)d_out;

    const int* src = eidx;
    const int* dst = eidx + N_EDGES;

    // ---- workspace layout (all offsets 16-B aligned) ----
    char* p = (char*)d_ws;
    float* dis   = (float*)p;  p += 20480 * 4;
    int*   cntI  = (int*)p;    p += 20480 * 4;
    int*   off   = (int*)p;    p += 20480 * 4;
    int*   cursor= (int*)p;    p += 20480 * 4;
    int*   perm  = (int*)p;    p += 20480 * 4;
    int*   gstart= (int*)p;    p += 128 * 4;
    int*   esrc  = (int*)p;    p += 402432 * 4;
    float* ew    = (float*)p;  p += 402432 * 4;
    ushort* xbf  = (ushort*)p; p += (size_t)NPAD * 1280 * 2;
    ushort* hbf  = (ushort*)p; p += (size_t)NPAD * 1280 * 2;
    ushort* abf  = (ushort*)p; p += (size_t)NPAD * 1280 * 2;
    float* a3f   = (float*)p;  p += (size_t)N_NODES * 320 * 4;
    ushort* Wt1  = (ushort*)p; p += (size_t)1280 * 1344 * 2;
    ushort* Wt2  = (ushort*)p; p += (size_t)640 * 1344 * 2;
    ushort* Wt3  = (ushort*)p; p += (size_t)320 * 704 * 2;
    float* pool  = (float*)p;  p += NGRAPH * 320 * 4;
    float* m1    = (float*)p;  p += NGRAPH * 1024 * 4;
    float* xc    = (float*)p;  p += NGRAPH * 208 * 4;
    float* f1    = (float*)p;  p += NGRAPH * 1024 * 4;
    float* f2    = (float*)p;  p += NGRAPH * 512 * 4;
    float* Wf1p  = (float*)p;  p += 208 * 1024 * 4;

    // ---- zero accumulators (stream-ordered, graph-capturable) ----
    hipMemsetAsync(cntI, 0, N_NODES * 4, stream);
    hipMemsetAsync(pool, 0, NGRAPH * 320 * 4, stream);

    // ---- all input-only preprocessing in one launch ----
    prep_mega<<<25000 + 2600 + 832 + 52 + 79, 256, 0, stream>>>(
        x, xbf, W1, Wt1, W2, Wt2, W3, Wt3, Wf1, Wf1p, fp_x, xc, batch, gstart);

    // ---- CSR build ----
    count_in<<<(N_EDGES + 255) / 256, 256, 0, stream>>>(dst, cntI);
    build_perm<<<1, 1024, 0, stream>>>(cntI, perm);
    scan_offsets<<<1, 1024, 0, stream>>>(cntI, off, cursor, dis);
    fill_csr<<<(N_EDGES + N_NODES + 255) / 256, 256, 0, stream>>>(src, dst, dis, cursor, esrc, ew);
    fill_pad<<<(N_NODES + 255) / 256, 256, 0, stream>>>(off, cursor, esrc, ew);

    // ---- layer 1 ----
    launch_gemm(xbf, Wt1, hbf, N_NODES, 1280, 1344, 1280, stream);
    launch_gather(hbf, off, esrc, ew, b1, abf, (float*)nullptr, perm, 1, 0, 20, stream);
    // ---- layer 2 ----
    launch_gemm(abf, Wt2, hbf, N_NODES, 1280, 1344, 640, stream);
    launch_gather(hbf, off, esrc, ew, b2, abf, (float*)nullptr, perm, 1, 0, 10, stream);
    // ---- layer 3 ----
    launch_gemm(abf, Wt3, hbf, N_NODES, 640, 704, 320, stream);
    launch_gather(hbf, off, esrc, ew, b3, (ushort*)nullptr, a3f, perm, 0, 1, 5, stream);

    // ---- global mean pool (partials; 1/cnt folded into g1 GEMM) ----
    pool_partial<<<dim3(NGRAPH, 4), 320, 0, stream>>>(a3f, gstart, pool);

    // ---- MLP head (split-K) ----
    head_gemm_sk<320, 4, 1, 1><<<(NGRAPH * 1024 * 4 + 255) / 256, 256, 0, stream>>>(
        pool, 320, Wg1, bg1, m1, NGRAPH, 1024, 1024, 0, gstart);
    head_gemm_sk<1024, 8, 0, 0><<<(NGRAPH * 128 * 8 + 255) / 256, 256, 0, stream>>>(
        m1, 1024, Wg2, bg2, xc, NGRAPH, 128, 208, FPD, (const int*)nullptr);
    head_gemm_sk<208, 4, 1, 0><<<(NGRAPH * 1024 * 4 + 255) / 256, 256, 0, stream>>>(
        xc, 208, Wf1p, bf1, f1, NGRAPH, 1024, 1024, 0, (const int*)nullptr);
    head_gemm_sk<1024, 8, 1, 0><<<(NGRAPH * 512 * 8 + 255) / 256, 256, 0, stream>>>(
        f1, 1024, Wf2, bf2, f2, NGRAPH, 512, 512, 0, (const int*)nullptr);
    head_out<<<NGRAPH, 256, 0, stream>>>(f2, Wo, bo, out);
}

// Round 12
// 638.445 us; speedup vs baseline: 1.1632x; 1.0399x over previous
//
#include <hip/hip_runtime.h>
#include <hip/hip_bf16.h>

#define N_NODES 20000
#define NPAD    20224          // node rows padded for tiled layout OOB-safe GEMM reads
#define N_EDGES 320000
#define NGRAPH  64
#define FPD     65

typedef __attribute__((ext_vector_type(8))) __bf16 bf16x8;
typedef __attribute__((ext_vector_type(4))) float floatx4;
typedef __attribute__((ext_vector_type(8))) ushort ushort8v;

__device__ inline float bf2f(ushort u) {
    union { unsigned int i; float f; } c; c.i = ((unsigned int)u) << 16; return c.f;
}
__device__ inline ushort f2bf(float v) {
    __hip_bfloat16 h = __float2bfloat16(v);
    return *(ushort*)&h;
}
// async global->LDS, 16 B per lane; LDS dest must be wave-uniform-base + lane*16
__device__ __forceinline__ void gld_lds16(const ushort* g, ushort* l) {
    __builtin_amdgcn_global_load_lds(
        (const __attribute__((address_space(1))) unsigned int*)g,
        (__attribute__((address_space(3))) unsigned int*)l,
        16, 0, 0);
}

// ---------------- prep_mega: count_in + all input-only preprocessing in ONE launch ----
// block ranges: [0,1250) count_in | [1250,26250) conv | [26250,28850) W transposes |
// [28850,29682) Wf1 pad | [29682,29734) xc static | [29734,29813) graph_bounds
__global__ __launch_bounds__(256) void prep_mega(
    const int* __restrict__ dst, int* __restrict__ cnt,
    const float* __restrict__ x, ushort* __restrict__ xbf,
    const float* __restrict__ W1, ushort* __restrict__ Wt1,
    const float* __restrict__ W2, ushort* __restrict__ Wt2,
    const float* __restrict__ W3, ushort* __restrict__ Wt3,
    const float* __restrict__ Wf1, float* __restrict__ Wf1p,
    const float* __restrict__ fp, float* __restrict__ xc,
    const int* __restrict__ batch, int* __restrict__ gstart)
{
    __shared__ float tsh[32][33];
    int b = blockIdx.x;
    if (b < 1250) {                        // count_in: in-degree atomics (cnt pre-zeroed)
        int e = b * 256 + threadIdx.x;     // 1250*256 == N_EDGES exactly
        atomicAdd(&cnt[dst[e]], 1);
        return;
    }
    b -= 1250;
    if (b < 25000) {                       // conv: x[N][1280] f32 -> tiled bf16
        int idx = b * 256 + threadIdx.x;   // 25000*256 == 20000*320 exactly
        int n = idx / 320, f4 = idx % 320;
        float4 v = *(const float4*)(x + (size_t)n * 1280 + f4 * 4);
        ushort4 o;
        o.x = f2bf(v.x); o.y = f2bf(v.y); o.z = f2bf(v.z); o.w = f2bf(v.w);
        *(ushort4*)(xbf + (size_t)(f4 >> 4) * (NPAD * 64) + (size_t)n * 64 + (f4 & 15) * 4) = o;
        return;
    }
    b -= 25000;
    if (b < 2600) {                        // W transposes (KP-padded, L2 set-conflict-free)
        const float* W; ushort* Wt; int Nc, KP, kt, nt;
        if (b < 1600)      { W = W1; Wt = Wt1; Nc = 1280; KP = 1344; kt = b % 40; nt = b / 40; }
        else if (b < 2400) { int b2 = b - 1600; W = W2; Wt = Wt2; Nc = 640; KP = 1344; kt = b2 % 40; nt = b2 / 40; }
        else               { int b2 = b - 2400; W = W3; Wt = Wt3; Nc = 320; KP = 704;  kt = b2 % 20; nt = b2 / 20; }
        int k0 = kt * 32, n0 = nt * 32;
        int tx = threadIdx.x & 31, ty = threadIdx.x >> 5;
        #pragma unroll
        for (int i = 0; i < 4; ++i)
            tsh[ty + i * 8][tx] = W[(size_t)(k0 + ty + i * 8) * Nc + n0 + tx];
        __syncthreads();
        #pragma unroll
        for (int i = 0; i < 4; ++i)
            Wt[(size_t)(n0 + ty + i * 8) * KP + k0 + tx] = f2bf(tsh[tx][ty + i * 8]);
        return;
    }
    b -= 2600;
    if (b < 832) {                         // pad Wf1 [193][1024] -> [208][1024]
        int idx = b * 256 + threadIdx.x;
        int k = idx / 1024;
        Wf1p[idx] = (k < 193) ? Wf1[idx] : 0.f;
        return;
    }
    b -= 832;
    if (b < 52) {                          // xc static: fp part + zeros
        int idx = b * 256 + threadIdx.x;
        if (idx < NGRAPH * 208) {
            int g = idx / 208, j = idx % 208;
            xc[idx] = (j < FPD) ? fp[g * FPD + j] : 0.f;
        }
        return;
    }
    b -= 52;
    {                                      // graph_bounds
        int n = b * 256 + threadIdx.x;
        if (n >= N_NODES) return;
        int bb = batch[n];
        int bp = (n == 0) ? -1 : batch[n - 1];
        for (int g = bp + 1; g <= bb; ++g) gstart[g] = n;
        if (n == N_NODES - 1)
            for (int g = bb + 1; g <= NGRAPH; ++g) gstart[g] = N_NODES;
    }
}

// ---------------- scan + perm in one 2-block launch (both only read cnt) ----------------
// block 0: prefix-scan of padded (deg+1) counts + D^-1/2.
// block 1: degree-bucket permutation (kills gather wave divergence).
__global__ __launch_bounds__(1024) void scan_perm(const int* __restrict__ cnt,
                                                  int* __restrict__ off, int* __restrict__ cursor,
                                                  float* __restrict__ dis, int* __restrict__ perm) {
    __shared__ int part[1024];
    __shared__ int hist[64];
    __shared__ int hbase[64];
    int t = threadIdx.x;
    if (blockIdx.x == 0) {
        const int chunk = (N_NODES + 1023) / 1024;
        int lo = t * chunk, hi = min(lo + chunk, N_NODES);
        int s = 0;
        for (int i = lo; i < hi; ++i) s += (cnt[i] + 4) & ~3;   // (deg+1) padded to x4
        part[t] = s;
        __syncthreads();
        for (int d = 1; d < 1024; d <<= 1) {
            int v = (t >= d) ? part[t - d] : 0;
            __syncthreads();
            part[t] += v;
            __syncthreads();
        }
        int base = part[t] - s;
        for (int i = lo; i < hi; ++i) {
            int c = cnt[i] + 1;                 // + self-loop
            off[i] = base; cursor[i] = base;
            dis[i] = rsqrtf((float)c);
            base += (c + 3) & ~3;
        }
        if (t == 1023) off[N_NODES] = part[1023];
    } else {
        if (t < 64) hist[t] = 0;
        __syncthreads();
        for (int i = t; i < N_NODES; i += 1024) {
            int g = ((cnt[i] + 4) & ~3) >> 2;   // iteration count of node i
            atomicAdd(&hist[min(g, 63)], 1);
        }
        __syncthreads();
        if (t == 0) {
            int acc = 0;
            for (int b = 0; b < 64; ++b) { hbase[b] = acc; acc += hist[b]; }
        }
        __syncthreads();
        for (int i = t; i < N_NODES; i += 1024) {
            int g = ((cnt[i] + 4) & ~3) >> 2;
            int pos = atomicAdd(&hbase[min(g, 63)], 1);
            perm[pos] = i;
        }
    }
}

__global__ void fill_csr(const int* __restrict__ src, const int* __restrict__ dst,
                         const float* __restrict__ dis, int* cursor,
                         int* __restrict__ esrc, float* __restrict__ ew) {
    int e = blockIdx.x * blockDim.x + threadIdx.x;
    if (e >= N_EDGES + N_NODES) return;
    int s, d; float w;
    if (e < N_EDGES) { s = src[e]; d = dst[e]; w = dis[s] * dis[d]; }
    else { s = d = e - N_EDGES; w = dis[s] * dis[s]; }
    int pos = atomicAdd(&cursor[d], 1);
    esrc[pos] = s; ew[pos] = w;
}
// NOTE: fill_pad removed — esrc/ew are memset to 0 before fill_csr, so pad slots
// hold (node 0, weight 0.0): in-bounds reads contributing exactly zero.

// ---------------- bf16 MFMA GEMM, BK=64, 2-phase double-buffered LDS ----------------
// 8-granule XOR swizzle: LDS slot (row,g) holds global granule g^(row&7); reads undo it.

#define STAGE128(AsB, BsB, kt) do {                                                   \
    const ushort* Ak_ = A + (size_t)(kt) * (NPAD * 64);                               \
    const ushort* Bk_ = Bt + (size_t)(kt) * 64;                                       \
    _Pragma("unroll")                                                                 \
    for (int i_ = 0; i_ < 4; ++i_) {                                                  \
        int c_ = tid + i_ * 256;                                                      \
        int row_ = c_ >> 3, g_ = c_ & 7;                                              \
        gld_lds16(Ak_ + (size_t)(bm + row_) * 64 + (g_ ^ (row_ & 7)) * 8, &AsB[c_ * 8]); \
    }                                                                                 \
    _Pragma("unroll")                                                                 \
    for (int i_ = 0; i_ < 4; ++i_) {                                                  \
        int c_ = tid + i_ * 256;                                                      \
        int row_ = c_ >> 3, g_ = c_ & 7;                                              \
        gld_lds16(Bk_ + (size_t)(bn + row_) * KP + (g_ ^ (row_ & 7)) * 8, &BsB[c_ * 8]); \
    }                                                                                 \
} while (0)

#define COMPUTE128(AsB, BsB) do {                                                     \
    _Pragma("unroll")                                                                 \
    for (int ks = 0; ks < 2; ++ks) {                                                  \
        bf16x8 af[4], bfv[4];                                                         \
        _Pragma("unroll")                                                             \
        for (int t = 0; t < 4; ++t) {                                                 \
            int ra = wr * 64 + t * 16 + mr;                                           \
            af[t] = *(const bf16x8*)&AsB[ra * 64 + ((ks * 4 + quad) ^ (ra & 7)) * 8]; \
            int rb = wc * 64 + t * 16 + mr;                                           \
            bfv[t] = *(const bf16x8*)&BsB[rb * 64 + ((ks * 4 + quad) ^ (rb & 7)) * 8];\
        }                                                                             \
        _Pragma("unroll")                                                             \
        for (int tm = 0; tm < 4; ++tm)                                                \
            _Pragma("unroll")                                                         \
            for (int tn = 0; tn < 4; ++tn)                                            \
                acc[tm][tn] = __builtin_amdgcn_mfma_f32_16x16x32_bf16(af[tm], bfv[tn], acc[tm][tn], 0, 0, 0); \
    }                                                                                 \
} while (0)

__global__ __launch_bounds__(256) void gemm_bf16_128(
    const ushort* __restrict__ A, const ushort* __restrict__ Bt,
    ushort* __restrict__ C, int M, int K, int KP, int Nc, int nt, int total, int chunk)
{
    __shared__ ushort As0[128 * 64], As1[128 * 64];
    __shared__ ushort Bs0[128 * 64], Bs1[128 * 64];
    const int bi = blockIdx.x;
    const int tile = (bi & 7) * chunk + (bi >> 3);
    if (tile >= total) return;
    const int bm = (tile / nt) * 128, bn = (tile % nt) * 128;

    const int tid = threadIdx.x;
    const int wid = tid >> 6, lane = tid & 63;
    const int wr = wid >> 1, wc = wid & 1;
    const int quad = lane >> 4, mr = lane & 15;

    floatx4 acc[4][4];
    #pragma unroll
    for (int i = 0; i < 4; ++i)
        #pragma unroll
        for (int j = 0; j < 4; ++j)
            acc[i][j] = (floatx4){0.f, 0.f, 0.f, 0.f};

    const int NT = K >> 6;     // even for all layers (20 / 20 / 10)
    STAGE128(As0, Bs0, 0);
    __syncthreads();
    for (int kt = 0; kt < NT; kt += 2) {
        if (kt + 1 < NT) STAGE128(As1, Bs1, kt + 1);
        COMPUTE128(As0, Bs0);
        __syncthreads();
        if (kt + 1 < NT) {
            if (kt + 2 < NT) STAGE128(As0, Bs0, kt + 2);
            COMPUTE128(As1, Bs1);
            __syncthreads();
        }
    }

    ushort* Cc = C + (size_t)((bn >> 6) + wc) * (NPAD * 64);
    #pragma unroll
    for (int tm = 0; tm < 4; ++tm) {
        int rowb = bm + wr * 64 + tm * 16 + quad * 4;
        #pragma unroll
        for (int r = 0; r < 4; ++r) {
            int row = rowb + r;
            if (row < M) {
                #pragma unroll
                for (int tn = 0; tn < 4; ++tn)
                    Cc[(size_t)row * 64 + tn * 16 + mr] = f2bf(acc[tm][tn][r]);
            }
        }
    }
}

// legacy 256x64 tile (for Nc % 128 != 0, i.e. layer 3), BK=64, dbuf, tiled A/C
#define STAGE64(AsB, BsB, kt) do {                                                    \
    const ushort* Ak_ = A + (size_t)(kt) * (NPAD * 64);                               \
    const ushort* Bk_ = Bt + (size_t)(kt) * 64;                                       \
    _Pragma("unroll")                                                                 \
    for (int i_ = 0; i_ < 8; ++i_) {                                                  \
        int c_ = tid + i_ * 256;                                                      \
        int row_ = c_ >> 3, g_ = c_ & 7;                                              \
        gld_lds16(Ak_ + (size_t)(bm + row_) * 64 + (g_ ^ (row_ & 7)) * 8, &AsB[c_ * 8]); \
    }                                                                                 \
    _Pragma("unroll")                                                                 \
    for (int i_ = 0; i_ < 2; ++i_) {                                                  \
        int c_ = tid + i_ * 256;                                                      \
        int row_ = c_ >> 3, g_ = c_ & 7;                                              \
        gld_lds16(Bk_ + (size_t)(bn + row_) * KP + (g_ ^ (row_ & 7)) * 8, &BsB[c_ * 8]); \
    }                                                                                 \
} while (0)

#define COMPUTE64(AsB, BsB) do {                                                      \
    _Pragma("unroll")                                                                 \
    for (int ks = 0; ks < 2; ++ks) {                                                  \
        bf16x8 af[4], bfv[4];                                                         \
        _Pragma("unroll")                                                             \
        for (int t = 0; t < 4; ++t) {                                                 \
            int ra = wid * 64 + t * 16 + mr;                                          \
            af[t] = *(const bf16x8*)&AsB[ra * 64 + ((ks * 4 + quad) ^ (ra & 7)) * 8]; \
            int rb = t * 16 + mr;                                                     \
            bfv[t] = *(const bf16x8*)&BsB[rb * 64 + ((ks * 4 + quad) ^ (rb & 7)) * 8];\
        }                                                                             \
        _Pragma("unroll")                                                             \
        for (int tm = 0; tm < 4; ++tm)                                                \
            _Pragma("unroll")                                                         \
            for (int tn = 0; tn < 4; ++tn)                                            \
                acc[tm][tn] = __builtin_amdgcn_mfma_f32_16x16x32_bf16(af[tm], bfv[tn], acc[tm][tn], 0, 0, 0); \
    }                                                                                 \
} while (0)

__global__ __launch_bounds__(256) void gemm_bf16(
    const ushort* __restrict__ A, const ushort* __restrict__ Bt,
    ushort* __restrict__ C, int M, int K, int KP, int Nc, int nt, int total, int chunk)
{
    __shared__ ushort As0[256 * 64], As1[256 * 64];
    __shared__ ushort Bs0[64 * 64], Bs1[64 * 64];
    const int bi = blockIdx.x;
    const int tile = (bi & 7) * chunk + (bi >> 3);
    if (tile >= total) return;
    const int bm = (tile / nt) * 256, bn = (tile % nt) * 64;

    const int tid = threadIdx.x;
    const int wid = tid >> 6, lane = tid & 63;
    const int quad = lane >> 4, mr = lane & 15;

    floatx4 acc[4][4];
    #pragma unroll
    for (int i = 0; i < 4; ++i)
        #pragma unroll
        for (int j = 0; j < 4; ++j)
            acc[i][j] = (floatx4){0.f, 0.f, 0.f, 0.f};

    const int NT = K >> 6;     // 10 for layer 3
    STAGE64(As0, Bs0, 0);
    __syncthreads();
    for (int kt = 0; kt < NT; kt += 2) {
        if (kt + 1 < NT) STAGE64(As1, Bs1, kt + 1);
        COMPUTE64(As0, Bs0);
        __syncthreads();
        if (kt + 1 < NT) {
            if (kt + 2 < NT) STAGE64(As0, Bs0, kt + 2);
            COMPUTE64(As1, Bs1);
            __syncthreads();
        }
    }

    ushort* Cc = C + (size_t)(bn >> 6) * (NPAD * 64);
    #pragma unroll
    for (int tm = 0; tm < 4; ++tm) {
        int rowb = bm + wid * 64 + tm * 16 + quad * 4;
        #pragma unroll
        for (int r = 0; r < 4; ++r) {
            int row = rowb + r;
            if (row < M) {
                #pragma unroll
                for (int tn = 0; tn < 4; ++tn)
                    Cc[(size_t)row * 64 + tn * 16 + mr] = f2bf(acc[tm][tn][r]);
            }
        }
    }
}

static inline void launch_gemm(const ushort* A, const ushort* Bt, ushort* C,
                               int M, int K, int KP, int Nc, hipStream_t stream) {
    if (Nc % 128 == 0) {
        int mt = (M + 127) / 128, nt = Nc / 128;
        int total = mt * nt;
        int chunk = (total + 7) / 8;
        gemm_bf16_128<<<8 * chunk, 256, 0, stream>>>(A, Bt, C, M, K, KP, Nc, nt, total, chunk);
    } else {
        int mt = (M + 255) / 256, nt = Nc / 64;
        int total = mt * nt;
        int chunk = (total + 7) / 8;
        gemm_bf16<<<8 * chunk, 256, 0, stream>>>(A, Bt, C, M, K, KP, Nc, nt, total, chunk);
    }
}

// ---------------- CSR gather: tiled layout, degree-sorted nodes, balanced XCD chunks ----
// 2-deep software pipeline: granule i+1's edge record + 4 feature-row loads are issued
// BEFORE granule i's FMAs run on already-resident registers.
template<int TPN>
__global__ __launch_bounds__(256) void gather_tiled(
    const ushort* __restrict__ h, const int* __restrict__ off,
    const int* __restrict__ esrc, const float* __restrict__ ew,
    const float* __restrict__ bias, ushort* __restrict__ out_bf,
    float* __restrict__ out_f32, const int* __restrict__ perm,
    int wbf, int wf32, int nchunks, int nbpc, int cpx)
{
    constexpr int NPB = 256 / TPN;     // nodes per block
    const int bi = blockIdx.x;
    const int t2 = (bi & 7) * cpx + (bi >> 3);
    if (t2 >= nchunks * nbpc) return;
    const int c = t2 / nbpc, nb = t2 - c * nbpc;
    const int tid = threadIdx.x;
    const int g = tid / TPN, t = tid % TPN;
    const int np = nb * NPB + g;
    if (np >= N_NODES) return;
    const int n = perm[np];            // degree-sorted node id

    const ushort* hc = h + (size_t)c * (NPAD * 64) + t * 8;
    float acc[8];
    #pragma unroll
    for (int j = 0; j < 8; ++j) acc[j] = 0.f;

    const int e0 = off[n], e1 = off[n + 1];
    // peel: load granule 0
    int4   s4 = *(const int4*)(esrc + e0);
    float4 w4 = *(const float4*)(ew + e0);
    ushort8v v0 = *(const ushort8v*)(hc + (size_t)s4.x * 64);
    ushort8v v1 = *(const ushort8v*)(hc + (size_t)s4.y * 64);
    ushort8v v2 = *(const ushort8v*)(hc + (size_t)s4.z * 64);
    ushort8v v3 = *(const ushort8v*)(hc + (size_t)s4.w * 64);
    for (int e = e0 + 4; e < e1; e += 4) {
        int4   s4n = *(const int4*)(esrc + e);
        float4 w4n = *(const float4*)(ew + e);
        ushort8v u0 = *(const ushort8v*)(hc + (size_t)s4n.x * 64);
        ushort8v u1 = *(const ushort8v*)(hc + (size_t)s4n.y * 64);
        ushort8v u2 = *(const ushort8v*)(hc + (size_t)s4n.z * 64);
        ushort8v u3 = *(const ushort8v*)(hc + (size_t)s4n.w * 64);
        #pragma unroll
        for (int j = 0; j < 8; ++j)
            acc[j] += w4.x * bf2f(v0[j]) + w4.y * bf2f(v1[j])
                    + w4.z * bf2f(v2[j]) + w4.w * bf2f(v3[j]);
        v0 = u0; v1 = u1; v2 = u2; v3 = u3; w4 = w4n;
    }
    #pragma unroll
    for (int j = 0; j < 8; ++j)
        acc[j] += w4.x * bf2f(v0[j]) + w4.y * bf2f(v1[j])
                + w4.z * bf2f(v2[j]) + w4.w * bf2f(v3[j]);

    const int fb = c * 64 + t * 8;
    float4 b0 = *(const float4*)(bias + fb);
    float4 b1 = *(const float4*)(bias + fb + 4);
    float r[8];
    r[0] = fmaxf(acc[0] + b0.x, 0.f); r[1] = fmaxf(acc[1] + b0.y, 0.f);
    r[2] = fmaxf(acc[2] + b0.z, 0.f); r[3] = fmaxf(acc[3] + b0.w, 0.f);
    r[4] = fmaxf(acc[4] + b1.x, 0.f); r[5] = fmaxf(acc[5] + b1.y, 0.f);
    r[6] = fmaxf(acc[6] + b1.z, 0.f); r[7] = fmaxf(acc[7] + b1.w, 0.f);
    if (wbf) {
        ushort8v o;
        #pragma unroll
        for (int j = 0; j < 8; ++j) o[j] = f2bf(r[j]);
        *(ushort8v*)(out_bf + (size_t)c * (NPAD * 64) + (size_t)n * 64 + t * 8) = o;
    }
    if (wf32) {
        *(float4*)(out_f32 + (size_t)n * (nchunks * 64) + fb)     = make_float4(r[0], r[1], r[2], r[3]);
        *(float4*)(out_f32 + (size_t)n * (nchunks * 64) + fb + 4) = make_float4(r[4], r[5], r[6], r[7]);
    }
}

static inline void launch_gather(const ushort* h, const int* off, const int* esrc,
                                 const float* ew, const float* bias, ushort* out_bf,
                                 float* out_f32, const int* perm,
                                 int wbf, int wf32, int nchunks, hipStream_t stream) {
    constexpr int TPN = 8;
    constexpr int NPB = 256 / TPN;
    const int nbpc = (N_NODES + NPB - 1) / NPB;
    const int total = nchunks * nbpc;
    const int cpx = (total + 7) / 8;
    gather_tiled<TPN><<<8 * cpx, 256, 0, stream>>>(
        h, off, esrc, ew, bias, out_bf, out_f32, perm, wbf, wf32, nchunks, nbpc, cpx);
}

// ---------------- mean pool: 4-way row-split partials, atomic accumulate ----------------
__global__ __launch_bounds__(320) void pool_partial(
    const float* __restrict__ x, const int* __restrict__ gstart, float* __restrict__ pool)
{
    int g = blockIdx.x, q = blockIdx.y;
    int t = threadIdx.x;
    int s = gstart[g], e = gstart[g + 1], len = e - s;
    int lo = s + (len * q) / 4, hi = s + (len * (q + 1)) / 4;
    float a0 = 0.f, a1 = 0.f, a2 = 0.f, a3 = 0.f;
    int n = lo;
    for (; n + 3 < hi; n += 4) {
        a0 += x[(size_t)(n + 0) * 320 + t];
        a1 += x[(size_t)(n + 1) * 320 + t];
        a2 += x[(size_t)(n + 2) * 320 + t];
        a3 += x[(size_t)(n + 3) * 320 + t];
    }
    for (; n < hi; ++n) a0 += x[(size_t)n * 320 + t];
    float acc = (a0 + a1) + (a2 + a3);
    if (hi > lo) atomicAdd(&pool[g * 320 + t], acc);
}

// ---------------- MLP head: split-K GEMM ----------------
template<int K, int SPLIT, int RELU, int SCALE>
__global__ __launch_bounds__(256) void head_gemm_sk(
    const float* __restrict__ in, int istride,
    const float* __restrict__ W, const float* __restrict__ b,
    float* __restrict__ out, int M, int Nc, int ostride, int ooff,
    const int* __restrict__ gs)
{
    constexpr int KQ = K / SPLIT;
    int idx = blockIdx.x * blockDim.x + threadIdx.x;
    int oi = idx / SPLIT, r = idx % SPLIT;
    if (oi >= M * Nc) return;
    int m = oi / Nc, c = oi % Nc;
    const float* ip = in + (size_t)m * istride + r * KQ;
    const float* wp = W + (size_t)r * KQ * Nc + c;
    float a0 = 0.f, a1 = 0.f, a2 = 0.f, a3 = 0.f;
    #pragma unroll
    for (int k = 0; k < KQ; k += 4) {
        float4 v = *(const float4*)(ip + k);
        a0 += v.x * wp[(size_t)(k + 0) * Nc];
        a1 += v.y * wp[(size_t)(k + 1) * Nc];
        a2 += v.z * wp[(size_t)(k + 2) * Nc];
        a3 += v.w * wp[(size_t)(k + 3) * Nc];
    }
    float s = (a0 + a1) + (a2 + a3);
    #pragma unroll
    for (int o = 1; o < SPLIT; o <<= 1) s += __shfl_xor(s, o, 64);
    if (r == 0) {
        if (SCALE) {
            float len = (float)(gs[m + 1] - gs[m]);
            s *= 1.f / fmaxf(len, 1.f);
        }
        s += b[c];
        out[(size_t)m * ostride + ooff + c] = RELU ? fmaxf(s, 0.f) : s;
    }
}

__global__ __launch_bounds__(256) void head_out(
    const float* __restrict__ f2, const float* __restrict__ Wo,
    const float* __restrict__ bo, float* __restrict__ out)
{
    int m = blockIdx.x;
    int t = threadIdx.x;
    float2 v = *(const float2*)(f2 + (size_t)m * 512 + t * 2);
    float2 w = *(const float2*)(Wo + t * 2);
    float s = v.x * w.x + v.y * w.y;
    #pragma unroll
    for (int o = 32; o > 0; o >>= 1) s += __shfl_down(s, o, 64);
    __shared__ float ps[4];
    if ((t & 63) == 0) ps[t >> 6] = s;
    __syncthreads();
    if (t == 0) out[m] = ps[0] + ps[1] + ps[2] + ps[3] + bo[0];
}

extern "C" void kernel_launch(void* const* d_in, const int* in_sizes, int n_in,
                              void* d_out, int out_size, void* d_ws, size_t ws_size,
                              hipStream_t stream) {
    const float* x    = (const float*)d_in[0];
    const int*   eidx = (const int*)d_in[1];
    const int*   batch= (const int*)d_in[2];
    const float* fp_x = (const float*)d_in[3];
    const float* W1 = (const float*)d_in[4];  const float* b1 = (const float*)d_in[5];
    const float* W2 = (const float*)d_in[6];  const float* b2 = (const float*)d_in[7];
    const float* W3 = (const float*)d_in[8];  const float* b3 = (const float*)d_in[9];
    const float* Wg1= (const float*)d_in[10]; const float* bg1= (const float*)d_in[11];
    const float* Wg2= (const float*)d_in[12]; const float* bg2= (const float*)d_in[13];
    const float* Wf1= (const float*)d_in[14]; const float* bf1= (const float*)d_in[15];
    const float* Wf2= (const float*)d_in[16]; const float* bf2= (const float*)d_in[17];
    const float* Wo = (const float*)d_in[18]; const float* bo = (const float*)d_in[19];
    float* out = (float*)d_out;

    const int* src = eidx;
    const int* dst = eidx + N_EDGES;

    // ---- workspace layout (all offsets 16-B aligned) ----
    char* p = (char*)d_ws;
    float* dis   = (float*)p;  p += 20480 * 4;
    int*   cntI  = (int*)p;    p += 20480 * 4;
    int*   off   = (int*)p;    p += 20480 * 4;
    int*   cursor= (int*)p;    p += 20480 * 4;
    int*   perm  = (int*)p;    p += 20480 * 4;
    int*   gstart= (int*)p;    p += 128 * 4;
    int*   esrc  = (int*)p;    p += 402432 * 4;
    float* ew    = (float*)p;  p += 402432 * 4;
    ushort* xbf  = (ushort*)p; p += (size_t)NPAD * 1280 * 2;
    ushort* hbf  = (ushort*)p; p += (size_t)NPAD * 1280 * 2;
    ushort* abf  = (ushort*)p; p += (size_t)NPAD * 1280 * 2;
    float* a3f   = (float*)p;  p += (size_t)N_NODES * 320 * 4;
    ushort* Wt1  = (ushort*)p; p += (size_t)1280 * 1344 * 2;
    ushort* Wt2  = (ushort*)p; p += (size_t)640 * 1344 * 2;
    ushort* Wt3  = (ushort*)p; p += (size_t)320 * 704 * 2;
    float* pool  = (float*)p;  p += NGRAPH * 320 * 4;
    float* m1    = (float*)p;  p += NGRAPH * 1024 * 4;
    float* xc    = (float*)p;  p += NGRAPH * 208 * 4;
    float* f1    = (float*)p;  p += NGRAPH * 1024 * 4;
    float* f2    = (float*)p;  p += NGRAPH * 512 * 4;
    float* Wf1p  = (float*)p;  p += 208 * 1024 * 4;

    // ---- zero accumulators + pad defaults (stream-ordered, graph-capturable) ----
    hipMemsetAsync(cntI, 0, N_NODES * 4, stream);
    hipMemsetAsync(pool, 0, NGRAPH * 320 * 4, stream);
    hipMemsetAsync(esrc, 0, 402432 * 4, stream);    // pad slots -> node 0
    hipMemsetAsync(ew,   0, 402432 * 4, stream);    // pad slots -> weight 0 (no-op)

    // ---- count_in + all input-only preprocessing in one launch ----
    prep_mega<<<1250 + 25000 + 2600 + 832 + 52 + 79, 256, 0, stream>>>(
        dst, cntI, x, xbf, W1, Wt1, W2, Wt2, W3, Wt3, Wf1, Wf1p, fp_x, xc, batch, gstart);

    // ---- CSR build (scan + perm concurrent in one launch; no fill_pad needed) ----
    scan_perm<<<2, 1024, 0, stream>>>(cntI, off, cursor, dis, perm);
    fill_csr<<<(N_EDGES + N_NODES + 255) / 256, 256, 0, stream>>>(src, dst, dis, cursor, esrc, ew);

    // ---- layer 1 ----
    launch_gemm(xbf, Wt1, hbf, N_NODES, 1280, 1344, 1280, stream);
    launch_gather(hbf, off, esrc, ew, b1, abf, (float*)nullptr, perm, 1, 0, 20, stream);
    // ---- layer 2 ----
    launch_gemm(abf, Wt2, hbf, N_NODES, 1280, 1344, 640, stream);
    launch_gather(hbf, off, esrc, ew, b2, abf, (float*)nullptr, perm, 1, 0, 10, stream);
    // ---- layer 3 ----
    launch_gemm(abf, Wt3, hbf, N_NODES, 640, 704, 320, stream);
    launch_gather(hbf, off, esrc, ew, b3, (ushort*)nullptr, a3f, perm, 0, 1, 5, stream);

    // ---- global mean pool (partials; 1/cnt folded into g1 GEMM) ----
    pool_partial<<<dim3(NGRAPH, 4), 320, 0, stream>>>(a3f, gstart, pool);

    // ---- MLP head (split-K) ----
    head_gemm_sk<320, 4, 1, 1><<<(NGRAPH * 1024 * 4 + 255) / 256, 256, 0, stream>>>(
        pool, 320, Wg1, bg1, m1, NGRAPH, 1024, 1024, 0, gstart);
    head_gemm_sk<1024, 8, 0, 0><<<(NGRAPH * 128 * 8 + 255) / 256, 256, 0, stream>>>(
        m1, 1024, Wg2, bg2, xc, NGRAPH, 128, 208, FPD, (const int*)nullptr);
    head_gemm_sk<208, 4, 1, 0><<<(NGRAPH * 1024 * 4 + 255) / 256, 256, 0, stream>>>(
        xc, 208, Wf1p, bf1, f1, NGRAPH, 1024, 1024, 0, (const int*)nullptr);
    head_gemm_sk<1024, 8, 1, 0><<<(NGRAPH * 512 * 8 + 255) / 256, 256, 0, stream>>>(
        f1, 1024, Wf2, bf2, f2, NGRAPH, 512, 512, 0, (const int*)nullptr);
    head_out<<<NGRAPH, 256, 0, stream>>>(f2, Wo, bo, out);
}